// Round 4
// baseline (56.828 us; speedup 1.0000x reference)
//
#include <hip/hip_runtime.h>

// MultiOrdinalCutoffs: B=524288 rows, T=16 tasks, Cmax=63 padded cutoffs.
// diff[b,c] = mask ? input[b] - weights[ids[b],c] : 0
// pos [b,c] = weights[ids[b],c]   (weights are zero-padded, so no mask needed)
// mask = c < lengths[ids[b]]
// Outputs concatenated flat: diff [B*63] then pos [B*63], float32.
//
// Write-bound: 264 MB stores vs ~4 MB reads. Floor at pure-write BW
// (~7.2 TB/s, per harness fill kernels) ≈ 37 µs.
//
// Tricks:
//  - (w, m) interleaved float2 LDS table (m = 0/1 mask): diff = fma(x,m,-w);
//    invalid slots give ±0 which matches the reference's 0 at absmax 0.
//  - pos = w directly (padding already zeroed in the input table).
//  - per-row (x, bitcast(row elem offset)) packed in one b64 read.
//  - nontemporal float4 stores via native vector type (evict-first hint).

#define CMAX 63
#define NTASK 16
#define ROWS_PER_BLOCK 256
#define ELEMS_PER_BLOCK (ROWS_PER_BLOCK * CMAX)   // 16128
#define VECS_PER_BLOCK (ELEMS_PER_BLOCK / 4)      // 4032 -> 16 iters of 256

typedef float f32x4 __attribute__((ext_vector_type(4)));

__global__ __launch_bounds__(256) void moc_kernel(
    const float* __restrict__ inp,      // [B]
    const int* __restrict__ ids,        // [B]
    const float* __restrict__ weights,  // [NTASK * CMAX]
    const int* __restrict__ lengths,    // [NTASK]
    float* __restrict__ out_diff,       // [B*CMAX]
    float* __restrict__ out_pos,        // [B*CMAX]
    int B)
{
    __shared__ float2 wm_lds[NTASK * CMAX];      // (w, mask) pairs, 8064 B
    __shared__ float2 row_lds[ROWS_PER_BLOCK];   // (x, bitcast(row elem offset))

    const int tid = threadIdx.x;

    // Build (w, m) table: 1008 entries, ~4 per thread. One-time cost.
    for (int i = tid; i < NTASK * CMAX; i += ROWS_PER_BLOCK) {
        const int t = i / CMAX;
        const int c = i - t * CMAX;
        const float w = weights[i];
        const float m = (c < lengths[t]) ? 1.0f : 0.0f;
        wm_lds[i] = make_float2(w, m);
    }

    // Stage this block's 256 rows: coalesced loads, packed per-row pair.
    const int row = blockIdx.x * ROWS_PER_BLOCK + tid;
    if (row < B) {
        const int t = ids[row];
        float2 r;
        r.x = inp[row];
        r.y = __int_as_float(t * CMAX);   // element offset of row t in wm_lds
        row_lds[tid] = r;
    }
    __syncthreads();

    // Hot loop: per element one b64 row read (mostly broadcast), one b64
    // (w,m) read, one fma; two nontemporal dwordx4 stores per iteration.
    const int ebase = blockIdx.x * ELEMS_PER_BLOCK;
    f32x4* __restrict__ od = reinterpret_cast<f32x4*>(out_diff + ebase);
    f32x4* __restrict__ op = reinterpret_cast<f32x4*>(out_pos + ebase);

#pragma unroll 4
    for (int k = 0; k < VECS_PER_BLOCK / ROWS_PER_BLOCK + 1; ++k) {
        const int v = tid + k * ROWS_PER_BLOCK;
        if (v >= VECS_PER_BLOCK) break;
        const int lbase = v << 2;   // local element index of component 0
        f32x4 dv, pv;
#pragma unroll
        for (int j = 0; j < 4; ++j) {
            const int li = lbase + j;
            const int bl = li / CMAX;           // magic-mul, constant 63
            const int c  = li - bl * CMAX;
            const float2 r  = row_lds[bl];      // (x, rowOff) ~broadcast
            const int rowOff = __float_as_int(r.y);
            const float2 wm = wm_lds[rowOff + c];
            dv[j] = __builtin_fmaf(r.x, wm.y, -wm.x);  // valid: x-w; else ±0
            pv[j] = wm.x;                               // padding already 0
        }
        __builtin_nontemporal_store(dv, &od[v]);
        __builtin_nontemporal_store(pv, &op[v]);
    }
}

extern "C" void kernel_launch(void* const* d_in, const int* in_sizes, int n_in,
                              void* d_out, int out_size, void* d_ws, size_t ws_size,
                              hipStream_t stream) {
    const float* inp     = (const float*)d_in[0];   // [B,1]
    const int*   ids     = (const int*)d_in[1];     // [B]
    const float* weights = (const float*)d_in[2];   // [T, Cmax]
    const int*   lengths = (const int*)d_in[3];     // [T]

    const int B = in_sizes[0];            // 524288 = 2048 * 256
    const int total = B * CMAX;
    float* out_diff = (float*)d_out;
    float* out_pos  = (float*)d_out + total;

    const int grid = (B + ROWS_PER_BLOCK - 1) / ROWS_PER_BLOCK;  // 2048
    moc_kernel<<<grid, ROWS_PER_BLOCK, 0, stream>>>(inp, ids, weights, lengths,
                                                    out_diff, out_pos, B);
}

// Round 5
// 43.513 us; speedup vs baseline: 1.3060x; 1.3060x over previous
//
#include <hip/hip_runtime.h>

// MultiOrdinalCutoffs: B=524288 rows, T=16 tasks, Cmax=63 padded cutoffs.
// diff[b,c] = mask ? input[b] - weights[ids[b],c] : 0
// pos [b,c] = weights[ids[b],c]   (weights are zero-padded, so no mask needed)
// mask = c < lengths[ids[b]]
// Outputs concatenated flat: diff [B*63] then pos [B*63], float32.
//
// Write-bound: 264 MB stores vs ~4 MB reads. Floor at pure-write BW
// (~7.1 TB/s, per harness fill kernels) ≈ 37 µs + launch ≈ 41-43 µs.
//
// R4 lesson: __builtin_nontemporal_store REGRESSED 42.8 -> 56.8 µs on
// gfx950 — nt bypasses L2 write-coalescing, which is the fast path for
// streaming stores. Use normal float4 stores.
//
// Tricks kept:
//  - (w, m) interleaved float2 LDS table (m = 0/1 mask): diff = fma(x,m,-w);
//    invalid slots give ±0 which matches the reference's 0 at absmax 0.
//  - pos = w directly (padding already zeroed in the input table).
//  - per-row (x, bitcast(row elem offset)) packed in one b64 read.

#define CMAX 63
#define NTASK 16
#define ROWS_PER_BLOCK 256
#define ELEMS_PER_BLOCK (ROWS_PER_BLOCK * CMAX)   // 16128
#define VECS_PER_BLOCK (ELEMS_PER_BLOCK / 4)      // 4032 -> 15 full + 1 partial iter

__global__ __launch_bounds__(256) void moc_kernel(
    const float* __restrict__ inp,      // [B]
    const int* __restrict__ ids,        // [B]
    const float* __restrict__ weights,  // [NTASK * CMAX]
    const int* __restrict__ lengths,    // [NTASK]
    float* __restrict__ out_diff,       // [B*CMAX]
    float* __restrict__ out_pos,        // [B*CMAX]
    int B)
{
    __shared__ float2 wm_lds[NTASK * CMAX];      // (w, mask) pairs, 8064 B
    __shared__ float2 row_lds[ROWS_PER_BLOCK];   // (x, bitcast(row elem offset))

    const int tid = threadIdx.x;

    // Build (w, m) table: 1008 entries, ~4 per thread. One-time cost.
    for (int i = tid; i < NTASK * CMAX; i += ROWS_PER_BLOCK) {
        const int t = i / CMAX;
        const int c = i - t * CMAX;
        const float w = weights[i];
        const float m = (c < lengths[t]) ? 1.0f : 0.0f;
        wm_lds[i] = make_float2(w, m);
    }

    // Stage this block's 256 rows: coalesced loads, packed per-row pair.
    const int row = blockIdx.x * ROWS_PER_BLOCK + tid;
    if (row < B) {
        const int t = ids[row];
        float2 r;
        r.x = inp[row];
        r.y = __int_as_float(t * CMAX);   // element offset of row t in wm_lds
        row_lds[tid] = r;
    }
    __syncthreads();

    // Hot loop: per element one b64 row read (mostly broadcast), one b64
    // (w,m) read, one fma; two dwordx4 stores per iteration.
    const int ebase = blockIdx.x * ELEMS_PER_BLOCK;
    float4* __restrict__ od = reinterpret_cast<float4*>(out_diff + ebase);
    float4* __restrict__ op = reinterpret_cast<float4*>(out_pos + ebase);

#pragma unroll 4
    for (int k = 0; k < VECS_PER_BLOCK / ROWS_PER_BLOCK + 1; ++k) {
        const int v = tid + k * ROWS_PER_BLOCK;
        if (v >= VECS_PER_BLOCK) break;
        const int lbase = v << 2;   // local element index of component 0
        float4 dv, pv;
        float* dvp = &dv.x;
        float* pvp = &pv.x;
#pragma unroll
        for (int j = 0; j < 4; ++j) {
            const int li = lbase + j;
            const int bl = li / CMAX;           // magic-mul, constant 63
            const int c  = li - bl * CMAX;
            const float2 r  = row_lds[bl];      // (x, rowOff) ~broadcast
            const int rowOff = __float_as_int(r.y);
            const float2 wm = wm_lds[rowOff + c];
            dvp[j] = __builtin_fmaf(r.x, wm.y, -wm.x);  // valid: x-w; else ±0
            pvp[j] = wm.x;                               // padding already 0
        }
        od[v] = dv;
        op[v] = pv;
    }
}

extern "C" void kernel_launch(void* const* d_in, const int* in_sizes, int n_in,
                              void* d_out, int out_size, void* d_ws, size_t ws_size,
                              hipStream_t stream) {
    const float* inp     = (const float*)d_in[0];   // [B,1]
    const int*   ids     = (const int*)d_in[1];     // [B]
    const float* weights = (const float*)d_in[2];   // [T, Cmax]
    const int*   lengths = (const int*)d_in[3];     // [T]

    const int B = in_sizes[0];            // 524288 = 2048 * 256
    const int total = B * CMAX;
    float* out_diff = (float*)d_out;
    float* out_pos  = (float*)d_out + total;

    const int grid = (B + ROWS_PER_BLOCK - 1) / ROWS_PER_BLOCK;  // 2048
    moc_kernel<<<grid, ROWS_PER_BLOCK, 0, stream>>>(inp, ids, weights, lengths,
                                                    out_diff, out_pos, B);
}

// Round 6
// 43.377 us; speedup vs baseline: 1.3101x; 1.0031x over previous
//
#include <hip/hip_runtime.h>

// MultiOrdinalCutoffs: B=524288 rows, T=16 tasks, Cmax=63 padded cutoffs.
// diff[b,c] = mask ? input[b] - weights[ids[b],c] : 0
// pos [b,c] = mask ? weights[ids[b],c]            : 0
// mask = c < lengths[ids[b]]
// Outputs concatenated flat: diff [B*63] then pos [B*63], float32.
//
// Write-bound: 264 MB stores vs ~4 MB reads. Demonstrated pure-write
// ceiling (harness fill kernels): ~7.1-7.28 TB/s -> floor ~37 µs + launch
// ~2 µs + read turnaround => 41-43 µs. This kernel: 42.8 µs (R2 measured).
//
// Ladder history:
//  R1 flat grid-stride, global loads in loop:        44.8 µs
//  R2 block-owns-256-rows, LDS-staged (x,t,len):     42.8 µs  <- this code
//  R4 + nontemporal stores:                          56.8 µs  (nt bypasses
//     L2 write-coalescing on gfx950 — never use for streaming stores)
//  R5 (w,m)-table fma slimming:                      43.5 µs  (VALU already
//     ~5% busy; arithmetic is free, stores are the wall)
//
// Structure: each block owns exactly 256 rows = 16128 elems = 4032 float4
// per output (exact: B = 2048*256). Per-row (x, t, len) staged in LDS via
// one coalesced dword load each; hot loop is LDS-read + float4-store only.

#define CMAX 63
#define NTASK 16
#define ROWS_PER_BLOCK 256
#define ELEMS_PER_BLOCK (ROWS_PER_BLOCK * CMAX)   // 16128
#define VECS_PER_BLOCK (ELEMS_PER_BLOCK / 4)      // 4032

__global__ __launch_bounds__(256) void moc_kernel(
    const float* __restrict__ inp,      // [B]
    const int* __restrict__ ids,        // [B]
    const float* __restrict__ weights,  // [NTASK * CMAX]
    const int* __restrict__ lengths,    // [NTASK]
    float* __restrict__ out_diff,       // [B*CMAX]
    float* __restrict__ out_pos,        // [B*CMAX]
    int B)
{
    __shared__ float w_lds[NTASK * CMAX];        // 4032 B
    __shared__ float x_lds[ROWS_PER_BLOCK];      // per-row input
    __shared__ int   t_lds[ROWS_PER_BLOCK];      // per-row task id
    __shared__ int   len_lds[ROWS_PER_BLOCK];    // per-row valid length

    const int tid = threadIdx.x;

    // Stage cutoff table (4 KB, broadcast-read later).
    for (int i = tid; i < NTASK * CMAX; i += ROWS_PER_BLOCK)
        w_lds[i] = weights[i];

    // Stage this block's 256 rows: one coalesced dword load per array.
    const int row = blockIdx.x * ROWS_PER_BLOCK + tid;
    if (row < B) {
        const int t = ids[row];
        x_lds[tid]   = inp[row];
        t_lds[tid]   = t;
        len_lds[tid] = lengths[t];   // 16-entry table, L1-resident
    }
    __syncthreads();

    // Hot loop: 16 iterations of pure LDS-read + 2x global_store_dwordx4.
    const int ebase = blockIdx.x * ELEMS_PER_BLOCK;
    float4* __restrict__ od = reinterpret_cast<float4*>(out_diff + ebase);
    float4* __restrict__ op = reinterpret_cast<float4*>(out_pos + ebase);

    for (int v = tid; v < VECS_PER_BLOCK; v += ROWS_PER_BLOCK) {
        const int lbase = v << 2;   // local element index of component 0
        float4 dv, pv;
        float* dvp = &dv.x;
        float* pvp = &pv.x;
#pragma unroll
        for (int j = 0; j < 4; ++j) {
            const int li = lbase + j;
            const int bl = li / CMAX;           // magic-mul, constant 63
            const int c  = li - bl * CMAX;
            const float x   = x_lds[bl];        // ~broadcast across lanes
            const int   t   = t_lds[bl];
            const int   len = len_lds[bl];
            const float w   = w_lds[t * CMAX + c];
            const bool valid = c < len;
            dvp[j] = valid ? (x - w) : 0.0f;
            pvp[j] = valid ? w : 0.0f;
        }
        od[v] = dv;
        op[v] = pv;
    }
}

extern "C" void kernel_launch(void* const* d_in, const int* in_sizes, int n_in,
                              void* d_out, int out_size, void* d_ws, size_t ws_size,
                              hipStream_t stream) {
    const float* inp     = (const float*)d_in[0];   // [B,1]
    const int*   ids     = (const int*)d_in[1];     // [B]
    const float* weights = (const float*)d_in[2];   // [T, Cmax]
    const int*   lengths = (const int*)d_in[3];     // [T]

    const int B = in_sizes[0];            // 524288 = 2048 * 256
    const int total = B * CMAX;
    float* out_diff = (float*)d_out;
    float* out_pos  = (float*)d_out + total;

    const int grid = (B + ROWS_PER_BLOCK - 1) / ROWS_PER_BLOCK;  // 2048
    moc_kernel<<<grid, ROWS_PER_BLOCK, 0, stream>>>(inp, ids, weights, lengths,
                                                    out_diff, out_pos, B);
}